// Round 1
// baseline (250.849 us; speedup 1.0000x reference)
//
#include <hip/hip_runtime.h>
#include <stdint.h>

#define MDIM 16384
#define NDIM 1020
#define KDIM 2048
#define NPAD 1024

typedef __attribute__((ext_vector_type(4))) float f32x4;
typedef __attribute__((ext_vector_type(8))) short short8;

// f32 -> bf16 round-to-nearest-even (inputs are normal randoms; no NaN care needed)
__device__ __forceinline__ unsigned short f2bf(float f) {
    unsigned int u = __float_as_uint(f);
    unsigned int r = (u + 0x7FFFu + ((u >> 16) & 1u)) >> 16;
    return (unsigned short)r;
}

// ---------------------------------------------------------------------------
// Kernel 1: W [K=2048][N=1020] f32  ->  Wt [NPAD=1024][K=2048] bf16 (transposed)
// rows n in [1020,1024) are zero-filled so the GEMM needs no B-load masking.
// Each thread handles a 4n x 4k block. Reads coalesced along n; scattered 8B
// writes are absorbed by L2 (only 4 MiB total).
// ---------------------------------------------------------------------------
__global__ void prep_w_kernel(const float* __restrict__ W,
                              unsigned short* __restrict__ Wt) {
    const int id = blockIdx.x * 256 + threadIdx.x;  // 512 blocks * 256
    const int n0 = (id & 255) * 4;                  // 0..1020
    const int k0 = (id >> 8) * 4;                   // 0..2044
    float a[4][4];
    if (n0 < NDIM) {
#pragma unroll
        for (int i = 0; i < 4; ++i) {
            const float* p = W + (size_t)(k0 + i) * NDIM + n0;
            a[i][0] = p[0]; a[i][1] = p[1]; a[i][2] = p[2]; a[i][3] = p[3];
        }
    } else {
#pragma unroll
        for (int i = 0; i < 4; ++i)
#pragma unroll
            for (int j = 0; j < 4; ++j) a[i][j] = 0.f;
    }
#pragma unroll
    for (int j = 0; j < 4; ++j) {
        uint2 p;
        p.x = (unsigned)f2bf(a[0][j]) | ((unsigned)f2bf(a[1][j]) << 16);
        p.y = (unsigned)f2bf(a[2][j]) | ((unsigned)f2bf(a[3][j]) << 16);
        *(uint2*)(Wt + (size_t)(n0 + j) * KDIM + k0) = p;
    }
}

// ---------------------------------------------------------------------------
// Kernel 2: GEMM  out[M][N] = x[M][K] @ W[K][N] + b
// 128x128 block tile, BK=32, 256 threads = 4 waves in 2x2 (64x64 per wave),
// per-wave acc = 4x4 fragments of 16x16 (mfma_f32_16x16x32_bf16).
// A: reg-staged f32->bf16 into As[128][32] (k-contiguous).
// B: global_load_lds dwordx4 from pre-transposed bf16 Wt into Bs[128][32].
// A/B fragments use the IDENTICAL k-indexing (8 contiguous k per lane), so the
// MFMA's internal k order cancels; C/D map is the m89/m91 HW-verified one.
// ---------------------------------------------------------------------------
__global__ void gemm_kernel(const float* __restrict__ x,
                            const unsigned short* __restrict__ Wt,
                            const float* __restrict__ bias,
                            float* __restrict__ out) {
    __shared__ __align__(16) unsigned short As[128][32];
    __shared__ __align__(16) unsigned short Bs[128][32];

    const int tid  = threadIdx.x;
    const int lane = tid & 63;
    const int wid  = tid >> 6;
    const int wr   = wid >> 1;   // wave row (0..1)
    const int wc   = wid & 1;    // wave col (0..1)
    const int bn   = blockIdx.x; // 0..7
    const int bm   = blockIdx.y; // 0..127

    f32x4 acc[4][4];
#pragma unroll
    for (int i = 0; i < 4; ++i)
#pragma unroll
        for (int j = 0; j < 4; ++j) {
            f32x4 z = {0.f, 0.f, 0.f, 0.f};
            acc[i][j] = z;
        }

    const int arow = tid >> 3;  // 0..31 (A tile row within group of 32)
    const int akg  = tid & 7;   // k-group of 4 floats
    const float* xbase = x + (size_t)(bm * 128) * KDIM + akg * 4;

    // B staging: wave `wid` covers rows wid*32 + j*16 + (lane>>2), 16B per lane
    const unsigned short* wbase =
        Wt + (size_t)(bn * 128 + wid * 32 + (lane >> 2)) * KDIM + (lane & 3) * 8;

    for (int kt = 0; kt < KDIM; kt += 32) {
        // ---- stage A (f32 load, convert, ds_write_b64) ----
#pragma unroll
        for (int i = 0; i < 4; ++i) {
            const float4 v = *(const float4*)(xbase + (size_t)(i * 32 + arow) * KDIM + kt);
            uint2 p;
            p.x = (unsigned)f2bf(v.x) | ((unsigned)f2bf(v.y) << 16);
            p.y = (unsigned)f2bf(v.z) | ((unsigned)f2bf(v.w) << 16);
            *(uint2*)&As[i * 32 + arow][akg * 4] = p;
        }
        // ---- stage B (async global->LDS, 16B/lane) ----
#pragma unroll
        for (int j = 0; j < 2; ++j) {
            const unsigned short* src = wbase + (size_t)j * 16 * KDIM + kt;
            __builtin_amdgcn_global_load_lds(
                (const __attribute__((address_space(1))) unsigned int*)src,
                (__attribute__((address_space(3))) unsigned int*)(&Bs[wid * 32 + j * 16][0]),
                16, 0, 0);
        }
        __syncthreads();

        short8 af[4], bfr[4];
#pragma unroll
        for (int mi = 0; mi < 4; ++mi)
            af[mi] = *(const short8*)&As[wr * 64 + mi * 16 + (lane & 15)][(lane >> 4) * 8];
#pragma unroll
        for (int ni = 0; ni < 4; ++ni)
            bfr[ni] = *(const short8*)&Bs[wc * 64 + ni * 16 + (lane & 15)][(lane >> 4) * 8];

#pragma unroll
        for (int mi = 0; mi < 4; ++mi)
#pragma unroll
            for (int ni = 0; ni < 4; ++ni)
                acc[mi][ni] = __builtin_amdgcn_mfma_f32_16x16x32_bf16(
                    af[mi], bfr[ni], acc[mi][ni], 0, 0, 0);

        __syncthreads();
    }

    // ---- epilogue: bias add + store (C/D map: col=lane&15, row=(lane>>4)*4+r) ----
#pragma unroll
    for (int ni = 0; ni < 4; ++ni) {
        const int col = bn * 128 + wc * 64 + ni * 16 + (lane & 15);
        if (col < NDIM) {
            const float bv = bias[col];
#pragma unroll
            for (int mi = 0; mi < 4; ++mi) {
                const int row = bm * 128 + wr * 64 + mi * 16 + ((lane >> 4) << 2);
                float* op = out + (size_t)row * NDIM + col;
#pragma unroll
                for (int r = 0; r < 4; ++r)
                    op[(size_t)r * NDIM] = acc[mi][ni][r] + bv;
            }
        }
    }
}

// ---------------------------------------------------------------------------
// Kernel 3: activation. One wave per (row, span). Span = 51 cols:
//   col 0          -> tanh(outputs)
//   cols 1..50     -> softmax over ((outputs + gumbel(u)) / 0.2)
// Full-wave shfl_xor reductions (inactive lanes contribute -inf / 0).
// ---------------------------------------------------------------------------
__global__ void act_kernel(const float* __restrict__ outp,
                           const float* __restrict__ u,
                           float* __restrict__ dt) {
    const int lane  = threadIdx.x & 63;
    const int gwave = (blockIdx.x * 256 + threadIdx.x) >> 6;
    const int nwave = gridDim.x * 4;
    const int total = MDIM * 20;
    const float NEG_INF = -__builtin_inff();

    for (int unit = gwave; unit < total; unit += nwave) {
        const int row = unit / 20;
        const int sp  = unit - row * 20;
        const size_t base = (size_t)row * NDIM + sp * 51;

        float o = 0.f, uu = 0.5f;
        if (lane < 51) {
            o  = outp[base + lane];
            uu = u[base + lane];
        }
        const bool soft = (lane >= 1) && (lane < 51);

        // gumbel: -log(-log(max(u, 1e-9)))   (upper clip 1-1e-9 == 1.0f in f32)
        const float uc = fmaxf(uu, 1e-9f);
        const float g  = -__logf(-__logf(uc));
        float z = soft ? (o + g) * 5.0f : NEG_INF;

        float m = z;
#pragma unroll
        for (int off = 32; off; off >>= 1) m = fmaxf(m, __shfl_xor(m, off));
        float e = soft ? __expf(z - m) : 0.f;
        float s = e;
#pragma unroll
        for (int off = 32; off; off >>= 1) s += __shfl_xor(s, off);

        float res;
        if (lane == 0) {
            const float ex = __expf(-2.0f * fabsf(o));
            const float t  = (1.0f - ex) / (1.0f + ex);
            res = copysignf(t, o);
        } else {
            res = e / s;
        }
        if (lane < 51) dt[base + lane] = res;
    }
}

// ---------------------------------------------------------------------------
extern "C" void kernel_launch(void* const* d_in, const int* in_sizes, int n_in,
                              void* d_out, int out_size, void* d_ws, size_t ws_size,
                              hipStream_t stream) {
    const float* x = (const float*)d_in[0];
    const float* W = (const float*)d_in[1];
    const float* b = (const float*)d_in[2];
    const float* u = (const float*)d_in[3];
    float* out = (float*)d_out;                      // outputs [M][N]
    float* dt  = out + (size_t)MDIM * NDIM;          // data_t  [M][N]
    unsigned short* Wt = (unsigned short*)d_ws;      // bf16 [NPAD][K], 4 MiB

    prep_w_kernel<<<512, 256, 0, stream>>>(W, Wt);
    gemm_kernel<<<dim3(8, 128), 256, 0, stream>>>(x, Wt, b, out);
    act_kernel<<<8192, 256, 0, stream>>>(out, u, dt);
}

// Round 2
// 212.345 us; speedup vs baseline: 1.1813x; 1.1813x over previous
//
#include <hip/hip_runtime.h>
#include <stdint.h>

#define MDIM 16384
#define NDIM 1020
#define KDIM 2048
#define NPAD 1024

typedef __attribute__((ext_vector_type(4))) float f32x4;
typedef __attribute__((ext_vector_type(8))) short short8;

// f32 -> bf16 round-to-nearest-even
__device__ __forceinline__ unsigned short f2bf(float f) {
    unsigned int u = __float_as_uint(f);
    unsigned int r = (u + 0x7FFFu + ((u >> 16) & 1u)) >> 16;
    return (unsigned short)r;
}

// ---------------------------------------------------------------------------
// Kernel 1: W [K=2048][N=1020] f32 -> Wt [NPAD=1024][K=2048] bf16 (transposed)
// ---------------------------------------------------------------------------
__global__ void prep_w_kernel(const float* __restrict__ W,
                              unsigned short* __restrict__ Wt) {
    const int id = blockIdx.x * 256 + threadIdx.x;  // 512 blocks * 256
    const int n0 = (id & 255) * 4;                  // 0..1020
    const int k0 = (id >> 8) * 4;                   // 0..2044
    float a[4][4];
    if (n0 < NDIM) {
#pragma unroll
        for (int i = 0; i < 4; ++i) {
            const float* p = W + (size_t)(k0 + i) * NDIM + n0;
            a[i][0] = p[0]; a[i][1] = p[1]; a[i][2] = p[2]; a[i][3] = p[3];
        }
    } else {
#pragma unroll
        for (int i = 0; i < 4; ++i)
#pragma unroll
            for (int j = 0; j < 4; ++j) a[i][j] = 0.f;
    }
#pragma unroll
    for (int j = 0; j < 4; ++j) {
        uint2 p;
        p.x = (unsigned)f2bf(a[0][j]) | ((unsigned)f2bf(a[1][j]) << 16);
        p.y = (unsigned)f2bf(a[2][j]) | ((unsigned)f2bf(a[3][j]) << 16);
        *(uint2*)(Wt + (size_t)(n0 + j) * KDIM + k0) = p;
    }
}

// ---------------------------------------------------------------------------
// Kernel 1b: x [M][K] f32 -> Xb [M][K] bf16 (same layout, 8 elems/thread)
// ---------------------------------------------------------------------------
__global__ void prep_x_kernel(const float* __restrict__ x,
                              unsigned short* __restrict__ Xb) {
    const size_t total = (size_t)MDIM * KDIM;
    const size_t stride = (size_t)gridDim.x * 256 * 8;
    for (size_t i = ((size_t)blockIdx.x * 256 + threadIdx.x) * 8; i < total; i += stride) {
        const float4 v0 = *(const float4*)(x + i);
        const float4 v1 = *(const float4*)(x + i + 4);
        uint4 p;
        p.x = (unsigned)f2bf(v0.x) | ((unsigned)f2bf(v0.y) << 16);
        p.y = (unsigned)f2bf(v0.z) | ((unsigned)f2bf(v0.w) << 16);
        p.z = (unsigned)f2bf(v1.x) | ((unsigned)f2bf(v1.y) << 16);
        p.w = (unsigned)f2bf(v1.z) | ((unsigned)f2bf(v1.w) << 16);
        *(uint4*)(Xb + i) = p;
    }
}

// ---------------------------------------------------------------------------
// Kernel 2 (fast path): GEMM out[M][N] = Xb[M][K] @ Wt[N][K]^T + b
// m97 structure: 128x128 tile, BK=32, 4 waves (2x2 of 64x64), both operands
// staged via global_load_lds width=16 (zero VALU staging). Linear LDS; the
// per-lane GLOBAL source matches lds_base + lane*16 exactly (guide §5 caveat).
// ---------------------------------------------------------------------------
__global__ void gemm_bf_kernel(const unsigned short* __restrict__ Xb,
                               const unsigned short* __restrict__ Wt,
                               const float* __restrict__ bias,
                               float* __restrict__ out) {
    __shared__ __align__(16) unsigned short As[128][32];
    __shared__ __align__(16) unsigned short Bs[128][32];

    const int tid  = threadIdx.x;
    const int lane = tid & 63;
    const int wid  = tid >> 6;
    const int wr   = wid >> 1;   // wave row (0..1)
    const int wc   = wid & 1;    // wave col (0..1)
    const int bn   = blockIdx.x; // 0..7
    const int bm   = blockIdx.y; // 0..127

    f32x4 acc[4][4];
#pragma unroll
    for (int i = 0; i < 4; ++i)
#pragma unroll
        for (int j = 0; j < 4; ++j) {
            f32x4 z = {0.f, 0.f, 0.f, 0.f};
            acc[i][j] = z;
        }

    // staging source: wave wid, call j covers LDS rows j*64 + wid*16 .. +15;
    // lane l -> row += l>>2, k-halfword offset (l&3)*8 (16 B per lane).
    const unsigned short* abase =
        Xb + (size_t)(bm * 128 + wid * 16 + (lane >> 2)) * KDIM + (lane & 3) * 8;
    const unsigned short* bbase =
        Wt + (size_t)(bn * 128 + wid * 16 + (lane >> 2)) * KDIM + (lane & 3) * 8;

    for (int kt = 0; kt < KDIM; kt += 32) {
#pragma unroll
        for (int j = 0; j < 2; ++j) {
            __builtin_amdgcn_global_load_lds(
                (const __attribute__((address_space(1))) unsigned int*)(abase + (size_t)j * 64 * KDIM + kt),
                (__attribute__((address_space(3))) unsigned int*)(&As[j * 64 + wid * 16][0]),
                16, 0, 0);
        }
#pragma unroll
        for (int j = 0; j < 2; ++j) {
            __builtin_amdgcn_global_load_lds(
                (const __attribute__((address_space(1))) unsigned int*)(bbase + (size_t)j * 64 * KDIM + kt),
                (__attribute__((address_space(3))) unsigned int*)(&Bs[j * 64 + wid * 16][0]),
                16, 0, 0);
        }
        __syncthreads();

        short8 af[4], bfr[4];
#pragma unroll
        for (int mi = 0; mi < 4; ++mi)
            af[mi] = *(const short8*)&As[wr * 64 + mi * 16 + (lane & 15)][(lane >> 4) * 8];
#pragma unroll
        for (int ni = 0; ni < 4; ++ni)
            bfr[ni] = *(const short8*)&Bs[wc * 64 + ni * 16 + (lane & 15)][(lane >> 4) * 8];

#pragma unroll
        for (int mi = 0; mi < 4; ++mi)
#pragma unroll
            for (int ni = 0; ni < 4; ++ni)
                acc[mi][ni] = __builtin_amdgcn_mfma_f32_16x16x32_bf16(
                    af[mi], bfr[ni], acc[mi][ni], 0, 0, 0);

        __syncthreads();
    }

    // epilogue: bias add + store (C/D map: col=lane&15, row=(lane>>4)*4+r)
#pragma unroll
    for (int ni = 0; ni < 4; ++ni) {
        const int col = bn * 128 + wc * 64 + ni * 16 + (lane & 15);
        if (col < NDIM) {
            const float bv = bias[col];
#pragma unroll
            for (int mi = 0; mi < 4; ++mi) {
                const int row = bm * 128 + wr * 64 + mi * 16 + ((lane >> 4) << 2);
                float* op = out + (size_t)row * NDIM + col;
#pragma unroll
                for (int r = 0; r < 4; ++r)
                    op[(size_t)r * NDIM] = acc[mi][ni][r] + bv;
            }
        }
    }
}

// ---------------------------------------------------------------------------
// Kernel 2 (fallback if ws too small): previous reg-staged-A GEMM
// ---------------------------------------------------------------------------
__global__ void gemm_kernel(const float* __restrict__ x,
                            const unsigned short* __restrict__ Wt,
                            const float* __restrict__ bias,
                            float* __restrict__ out) {
    __shared__ __align__(16) unsigned short As[128][32];
    __shared__ __align__(16) unsigned short Bs[128][32];

    const int tid  = threadIdx.x;
    const int lane = tid & 63;
    const int wid  = tid >> 6;
    const int wr   = wid >> 1;
    const int wc   = wid & 1;
    const int bn   = blockIdx.x;
    const int bm   = blockIdx.y;

    f32x4 acc[4][4];
#pragma unroll
    for (int i = 0; i < 4; ++i)
#pragma unroll
        for (int j = 0; j < 4; ++j) {
            f32x4 z = {0.f, 0.f, 0.f, 0.f};
            acc[i][j] = z;
        }

    const int arow = tid >> 3;
    const int akg  = tid & 7;
    const float* xbase = x + (size_t)(bm * 128) * KDIM + akg * 4;
    const unsigned short* wbase =
        Wt + (size_t)(bn * 128 + wid * 32 + (lane >> 2)) * KDIM + (lane & 3) * 8;

    for (int kt = 0; kt < KDIM; kt += 32) {
#pragma unroll
        for (int i = 0; i < 4; ++i) {
            const float4 v = *(const float4*)(xbase + (size_t)(i * 32 + arow) * KDIM + kt);
            uint2 p;
            p.x = (unsigned)f2bf(v.x) | ((unsigned)f2bf(v.y) << 16);
            p.y = (unsigned)f2bf(v.z) | ((unsigned)f2bf(v.w) << 16);
            *(uint2*)&As[i * 32 + arow][akg * 4] = p;
        }
#pragma unroll
        for (int j = 0; j < 2; ++j) {
            const unsigned short* src = wbase + (size_t)j * 16 * KDIM + kt;
            __builtin_amdgcn_global_load_lds(
                (const __attribute__((address_space(1))) unsigned int*)src,
                (__attribute__((address_space(3))) unsigned int*)(&Bs[wid * 32 + j * 16][0]),
                16, 0, 0);
        }
        __syncthreads();

        short8 af[4], bfr[4];
#pragma unroll
        for (int mi = 0; mi < 4; ++mi)
            af[mi] = *(const short8*)&As[wr * 64 + mi * 16 + (lane & 15)][(lane >> 4) * 8];
#pragma unroll
        for (int ni = 0; ni < 4; ++ni)
            bfr[ni] = *(const short8*)&Bs[wc * 64 + ni * 16 + (lane & 15)][(lane >> 4) * 8];

#pragma unroll
        for (int mi = 0; mi < 4; ++mi)
#pragma unroll
            for (int ni = 0; ni < 4; ++ni)
                acc[mi][ni] = __builtin_amdgcn_mfma_f32_16x16x32_bf16(
                    af[mi], bfr[ni], acc[mi][ni], 0, 0, 0);

        __syncthreads();
    }

#pragma unroll
    for (int ni = 0; ni < 4; ++ni) {
        const int col = bn * 128 + wc * 64 + ni * 16 + (lane & 15);
        if (col < NDIM) {
            const float bv = bias[col];
#pragma unroll
            for (int mi = 0; mi < 4; ++mi) {
                const int row = bm * 128 + wr * 64 + mi * 16 + ((lane >> 4) << 2);
                float* op = out + (size_t)row * NDIM + col;
#pragma unroll
                for (int r = 0; r < 4; ++r)
                    op[(size_t)r * NDIM] = acc[mi][ni][r] + bv;
            }
        }
    }
}

// ---------------------------------------------------------------------------
// Kernel 3: activation. One wave per (row, span of 51 cols).
// ---------------------------------------------------------------------------
__global__ void act_kernel(const float* __restrict__ outp,
                           const float* __restrict__ u,
                           float* __restrict__ dt) {
    const int lane  = threadIdx.x & 63;
    const int gwave = (blockIdx.x * 256 + threadIdx.x) >> 6;
    const int nwave = gridDim.x * 4;
    const int total = MDIM * 20;
    const float NEG_INF = -__builtin_inff();

    for (int unit = gwave; unit < total; unit += nwave) {
        const int row = unit / 20;
        const int sp  = unit - row * 20;
        const size_t base = (size_t)row * NDIM + sp * 51;

        float o = 0.f, uu = 0.5f;
        if (lane < 51) {
            o  = outp[base + lane];
            uu = u[base + lane];
        }
        const bool soft = (lane >= 1) && (lane < 51);

        const float uc = fmaxf(uu, 1e-9f);
        const float g  = -__logf(-__logf(uc));
        float z = soft ? (o + g) * 5.0f : NEG_INF;

        float m = z;
#pragma unroll
        for (int off = 32; off; off >>= 1) m = fmaxf(m, __shfl_xor(m, off));
        float e = soft ? __expf(z - m) : 0.f;
        float s = e;
#pragma unroll
        for (int off = 32; off; off >>= 1) s += __shfl_xor(s, off);

        float res;
        if (lane == 0) {
            const float ex = __expf(-2.0f * fabsf(o));
            const float t  = (1.0f - ex) / (1.0f + ex);
            res = copysignf(t, o);
        } else {
            res = e / s;
        }
        if (lane < 51) dt[base + lane] = res;
    }
}

// ---------------------------------------------------------------------------
extern "C" void kernel_launch(void* const* d_in, const int* in_sizes, int n_in,
                              void* d_out, int out_size, void* d_ws, size_t ws_size,
                              hipStream_t stream) {
    const float* x = (const float*)d_in[0];
    const float* W = (const float*)d_in[1];
    const float* b = (const float*)d_in[2];
    const float* u = (const float*)d_in[3];
    float* out = (float*)d_out;                      // outputs [M][N]
    float* dt  = out + (size_t)MDIM * NDIM;          // data_t  [M][N]
    unsigned short* Wt = (unsigned short*)d_ws;      // bf16 [NPAD][K], 4 MiB

    prep_w_kernel<<<512, 256, 0, stream>>>(W, Wt);

    const size_t need = ((size_t)NPAD * KDIM + (size_t)MDIM * KDIM) * sizeof(unsigned short);
    if (ws_size >= need) {
        unsigned short* Xb = Wt + (size_t)NPAD * KDIM;  // bf16 [M][K], 64 MiB
        prep_x_kernel<<<2048, 256, 0, stream>>>(x, Xb);
        gemm_bf_kernel<<<dim3(8, 128), 256, 0, stream>>>(Xb, Wt, b, out);
    } else {
        gemm_kernel<<<dim3(8, 128), 256, 0, stream>>>(x, Wt, b, out);
    }

    act_kernel<<<8192, 256, 0, stream>>>(out, u, dt);
}

// Round 3
// 192.400 us; speedup vs baseline: 1.3038x; 1.1037x over previous
//
#include <hip/hip_runtime.h>
#include <stdint.h>

#define MDIM 16384
#define NDIM 1020
#define KDIM 2048
#define NPAD 1024
#define TK   (KDIM / 64)   // 32 K-tiles of BK=64

typedef __attribute__((ext_vector_type(4))) float f32x4;
typedef __attribute__((ext_vector_type(8))) short short8;

#define MFMA16(a, b, c) __builtin_amdgcn_mfma_f32_16x16x32_bf16((a), (b), (c), 0, 0, 0)

// f32 -> bf16 round-to-nearest-even
__device__ __forceinline__ unsigned short f2bf(float f) {
    unsigned int u = __float_as_uint(f);
    unsigned int r = (u + 0x7FFFu + ((u >> 16) & 1u)) >> 16;
    return (unsigned short)r;
}

// ---------------------------------------------------------------------------
// Kernel 1: W [K=2048][N=1020] f32 -> Wt [NPAD=1024][K=2048] bf16 (transposed)
// ---------------------------------------------------------------------------
__global__ void prep_w_kernel(const float* __restrict__ W,
                              unsigned short* __restrict__ Wt) {
    const int id = blockIdx.x * 256 + threadIdx.x;  // 512 blocks * 256
    const int n0 = (id & 255) * 4;
    const int k0 = (id >> 8) * 4;
    float a[4][4];
    if (n0 < NDIM) {
#pragma unroll
        for (int i = 0; i < 4; ++i) {
            const float* p = W + (size_t)(k0 + i) * NDIM + n0;
            a[i][0] = p[0]; a[i][1] = p[1]; a[i][2] = p[2]; a[i][3] = p[3];
        }
    } else {
#pragma unroll
        for (int i = 0; i < 4; ++i)
#pragma unroll
            for (int j = 0; j < 4; ++j) a[i][j] = 0.f;
    }
#pragma unroll
    for (int j = 0; j < 4; ++j) {
        uint2 p;
        p.x = (unsigned)f2bf(a[0][j]) | ((unsigned)f2bf(a[1][j]) << 16);
        p.y = (unsigned)f2bf(a[2][j]) | ((unsigned)f2bf(a[3][j]) << 16);
        *(uint2*)(Wt + (size_t)(n0 + j) * KDIM + k0) = p;
    }
}

// ---------------------------------------------------------------------------
// Kernel 1b: x [M][K] f32 -> Xb [M][K] bf16
// ---------------------------------------------------------------------------
__global__ void prep_x_kernel(const float* __restrict__ x,
                              unsigned short* __restrict__ Xb) {
    const size_t total = (size_t)MDIM * KDIM;
    const size_t stride = (size_t)gridDim.x * 256 * 8;
    for (size_t i = ((size_t)blockIdx.x * 256 + threadIdx.x) * 8; i < total; i += stride) {
        const float4 v0 = *(const float4*)(x + i);
        const float4 v1 = *(const float4*)(x + i + 4);
        uint4 p;
        p.x = (unsigned)f2bf(v0.x) | ((unsigned)f2bf(v0.y) << 16);
        p.y = (unsigned)f2bf(v0.z) | ((unsigned)f2bf(v0.w) << 16);
        p.z = (unsigned)f2bf(v1.x) | ((unsigned)f2bf(v1.y) << 16);
        p.w = (unsigned)f2bf(v1.z) | ((unsigned)f2bf(v1.w) << 16);
        *(uint4*)(Xb + i) = p;
    }
}

// ---------------------------------------------------------------------------
// Kernel 2: 256x256 8-phase GEMM (T1+T2+T3+T4+T5), BK=64, 512 thr / 8 waves
// (2 wr x 4 wc), per-wave C = 128x64 = 8mf x 4nf frags of 16x16.
// Phase p (of 4 per K-tile): ds-read A-frags mf={2p,2p+1} (+ all B at p0,
// persisted in regs); issue 2 stripe stages (global_load_lds w=16, linear LDS
// dest + pre-swizzled global source per rule 21); s_barrier; setprio(1);
// 16 MFMA; setprio(0); [vmcnt(4) at p3]; s_barrier.
// Stage schedule (stripe = 64 rows/cols = 1 gload/wave):
//   p0: A-stripes 1,3 of Kt t+1 -> nb   (nb regions last read at (t-1,p3))
//   p1: B-stripes 0,1 of Kt t+2 -> buf  (all B of Kt t read at p0)
//   p2: B-stripes 2,3 of Kt t+2 -> buf
//   p3: A-stripes 0,2 of Kt t+2 -> buf  (A stripes 0,2 last read at p1)
// vmcnt(4) at (t,p3) retires everything through (t,p1) => Kt t+1 fully
// landed before iteration t+1 reads it. Steady state 4-12 loads in flight.
// LDS swizzle: 16B block cb at (row, cb^(row&7)); reads are 2-way-bank (free).
// ---------------------------------------------------------------------------
extern "C" __global__ __launch_bounds__(512, 2) void gemm8_kernel(
    const unsigned short* __restrict__ Xb,
    const unsigned short* __restrict__ Wt,
    const float* __restrict__ bias,
    float* __restrict__ out) {
    extern __shared__ unsigned short lds_raw[];  // 2 bufs x (A 256x64 + B 256x64)

    const int tid  = threadIdx.x;
    const int lane = tid & 63;
    const int wid  = tid >> 6;   // 0..7
    const int wr   = wid >> 2;   // 0..1 (M)
    const int wc   = wid & 3;    // 0..3 (N)

    // XCD-aware swizzle: 256 blocks, 8 XCDs, 32 consecutive per XCD
    const int bid = blockIdx.x;
    const int swz = (bid & 7) * 32 + (bid >> 3);
    const int bm  = swz >> 2;    // 0..63
    const int bn  = swz & 3;     // 0..3

    // per-lane pre-swizzled staging source: row = +wid*8 + (lane>>3),
    // k-block = (lane&7)^(lane>>3)  (inverse of the read-side XOR swizzle)
    const int srow = wid * 8 + (lane >> 3);
    const int scb  = ((lane & 7) ^ (lane >> 3)) * 8;
    const unsigned short* aS = Xb + (size_t)(bm * 256 + srow) * KDIM + scb;
    const unsigned short* bS = Wt + (size_t)(bn * 256 + srow) * KDIM + scb;

#define LDS_A(B) (lds_raw + (B) * 32768)
#define LDS_B(B) (lds_raw + (B) * 32768 + 16384)

#define STAGE(BUFI, OP, STRIPE, S) do {                                          \
    const size_t ks_ = (size_t)(((S) * 64) & (KDIM - 1));                        \
    const unsigned short* sp_ =                                                  \
        ((OP) ? bS : aS) + (size_t)((STRIPE) * 64) * KDIM + ks_;                 \
    __builtin_amdgcn_global_load_lds(                                            \
        (const __attribute__((address_space(1))) unsigned int*)sp_,              \
        (__attribute__((address_space(3))) unsigned int*)(lds_raw +              \
            (BUFI) * 32768 + (OP) * 16384 + ((STRIPE) * 64 + wid * 8) * 64),     \
        16, 0, 0);                                                               \
} while (0)

#define LOAD_AF(DST, BUFI, MF) do {                                              \
    _Pragma("unroll")                                                            \
    for (int k2_ = 0; k2_ < 2; ++k2_) {                                          \
        const int cb_ = ((k2_ * 4 + (lane >> 4)) ^ (lane & 7)) * 8;              \
        DST[k2_] = *(const short8*)(LDS_A(BUFI) +                                \
            (wr * 128 + (MF) * 16 + (lane & 15)) * 64 + cb_);                    \
    }                                                                            \
} while (0)

#define VMCNT4 do {                                                              \
    asm volatile("s_waitcnt vmcnt(4)" ::: "memory");                             \
    __builtin_amdgcn_sched_barrier(0);                                           \
} while (0)

    f32x4 acc[8][4];
#pragma unroll
    for (int i = 0; i < 8; ++i)
#pragma unroll
        for (int j = 0; j < 4; ++j) {
            f32x4 z = {0.f, 0.f, 0.f, 0.f};
            acc[i][j] = z;
        }

    // ---- prologue: Kt0 all 8 stripes; Kt1 B0-3, A0, A2 (FIFO order) ----
    STAGE(0, 0, 0, 0); STAGE(0, 0, 1, 0); STAGE(0, 0, 2, 0); STAGE(0, 0, 3, 0);
    STAGE(0, 1, 0, 0); STAGE(0, 1, 1, 0); STAGE(0, 1, 2, 0); STAGE(0, 1, 3, 0);
    STAGE(1, 1, 0, 1); STAGE(1, 1, 1, 1); STAGE(1, 1, 2, 1); STAGE(1, 1, 3, 1);
    STAGE(1, 0, 0, 1); STAGE(1, 0, 2, 1);
    VMCNT4;                                  // Kt0 fully landed
    __builtin_amdgcn_s_barrier();

    for (int t = 0; t < TK; ++t) {
        const int buf = t & 1;
        const int nb  = buf ^ 1;
        short8 bfv[4][2];

        // ---- phase 0: all B frags + A mf{0,1}; stage A-stripes 1,3 (t+1) ----
        {
#pragma unroll
            for (int nf = 0; nf < 4; ++nf)
#pragma unroll
                for (int k2 = 0; k2 < 2; ++k2) {
                    const int cb = ((k2 * 4 + (lane >> 4)) ^ (lane & 7)) * 8;
                    bfv[nf][k2] = *(const short8*)(LDS_B(buf) +
                        (wc * 64 + nf * 16 + (lane & 15)) * 64 + cb);
                }
            short8 af0[2], af1[2];
            LOAD_AF(af0, buf, 0);
            LOAD_AF(af1, buf, 1);
            STAGE(nb, 0, 1, t + 1);
            STAGE(nb, 0, 3, t + 1);
            __builtin_amdgcn_s_barrier();
            __builtin_amdgcn_s_setprio(1);
#pragma unroll
            for (int nf = 0; nf < 4; ++nf) {
                acc[0][nf] = MFMA16(af0[0], bfv[nf][0], acc[0][nf]);
                acc[0][nf] = MFMA16(af0[1], bfv[nf][1], acc[0][nf]);
                acc[1][nf] = MFMA16(af1[0], bfv[nf][0], acc[1][nf]);
                acc[1][nf] = MFMA16(af1[1], bfv[nf][1], acc[1][nf]);
            }
            __builtin_amdgcn_s_setprio(0);
            __builtin_amdgcn_s_barrier();
        }
        // ---- phase 1: A mf{2,3}; stage B-stripes 0,1 (t+2) ----
        {
            short8 af0[2], af1[2];
            LOAD_AF(af0, buf, 2);
            LOAD_AF(af1, buf, 3);
            STAGE(buf, 1, 0, t + 2);
            STAGE(buf, 1, 1, t + 2);
            __builtin_amdgcn_s_barrier();
            __builtin_amdgcn_s_setprio(1);
#pragma unroll
            for (int nf = 0; nf < 4; ++nf) {
                acc[2][nf] = MFMA16(af0[0], bfv[nf][0], acc[2][nf]);
                acc[2][nf] = MFMA16(af0[1], bfv[nf][1], acc[2][nf]);
                acc[3][nf] = MFMA16(af1[0], bfv[nf][0], acc[3][nf]);
                acc[3][nf] = MFMA16(af1[1], bfv[nf][1], acc[3][nf]);
            }
            __builtin_amdgcn_s_setprio(0);
            __builtin_amdgcn_s_barrier();
        }
        // ---- phase 2: A mf{4,5}; stage B-stripes 2,3 (t+2) ----
        {
            short8 af0[2], af1[2];
            LOAD_AF(af0, buf, 4);
            LOAD_AF(af1, buf, 5);
            STAGE(buf, 1, 2, t + 2);
            STAGE(buf, 1, 3, t + 2);
            __builtin_amdgcn_s_barrier();
            __builtin_amdgcn_s_setprio(1);
#pragma unroll
            for (int nf = 0; nf < 4; ++nf) {
                acc[4][nf] = MFMA16(af0[0], bfv[nf][0], acc[4][nf]);
                acc[4][nf] = MFMA16(af0[1], bfv[nf][1], acc[4][nf]);
                acc[5][nf] = MFMA16(af1[0], bfv[nf][0], acc[5][nf]);
                acc[5][nf] = MFMA16(af1[1], bfv[nf][1], acc[5][nf]);
            }
            __builtin_amdgcn_s_setprio(0);
            __builtin_amdgcn_s_barrier();
        }
        // ---- phase 3: A mf{6,7}; stage A-stripes 0,2 (t+2); vmcnt(4) ----
        {
            short8 af0[2], af1[2];
            LOAD_AF(af0, buf, 6);
            LOAD_AF(af1, buf, 7);
            STAGE(buf, 0, 0, t + 2);
            STAGE(buf, 0, 2, t + 2);
            __builtin_amdgcn_s_barrier();
            __builtin_amdgcn_s_setprio(1);
#pragma unroll
            for (int nf = 0; nf < 4; ++nf) {
                acc[6][nf] = MFMA16(af0[0], bfv[nf][0], acc[6][nf]);
                acc[6][nf] = MFMA16(af0[1], bfv[nf][1], acc[6][nf]);
                acc[7][nf] = MFMA16(af1[0], bfv[nf][0], acc[7][nf]);
                acc[7][nf] = MFMA16(af1[1], bfv[nf][1], acc[7][nf]);
            }
            __builtin_amdgcn_s_setprio(0);
            VMCNT4;
            __builtin_amdgcn_s_barrier();
        }
    }

    // ---- epilogue: bias + store (C/D: col=lane&15, row=(lane>>4)*4+r) ----
#pragma unroll
    for (int nf = 0; nf < 4; ++nf) {
        const int col = bn * 256 + wc * 64 + nf * 16 + (lane & 15);
        if (col < NDIM) {
            const float bv = bias[col];
#pragma unroll
            for (int mf = 0; mf < 8; ++mf) {
                const int row = bm * 256 + wr * 128 + mf * 16 + ((lane >> 4) << 2);
                float* op = out + (size_t)row * NDIM + col;
#pragma unroll
                for (int r = 0; r < 4; ++r)
                    op[(size_t)r * NDIM] = acc[mf][nf][r] + bv;
            }
        }
    }
#undef LDS_A
#undef LDS_B
#undef STAGE
#undef LOAD_AF
#undef VMCNT4
}

// ---------------------------------------------------------------------------
// Fallback GEMM (round-2, 64 KiB static LDS) if dynamic-LDS attr fails
// ---------------------------------------------------------------------------
__global__ void gemm_bf_kernel(const unsigned short* __restrict__ Xb,
                               const unsigned short* __restrict__ Wt,
                               const float* __restrict__ bias,
                               float* __restrict__ out) {
    __shared__ __align__(16) unsigned short As[128][32];
    __shared__ __align__(16) unsigned short Bs[128][32];

    const int tid  = threadIdx.x;
    const int lane = tid & 63;
    const int wid  = tid >> 6;
    const int wr   = wid >> 1;
    const int wc   = wid & 1;
    const int bn   = blockIdx.x;
    const int bm   = blockIdx.y;

    f32x4 acc[4][4];
#pragma unroll
    for (int i = 0; i < 4; ++i)
#pragma unroll
        for (int j = 0; j < 4; ++j) {
            f32x4 z = {0.f, 0.f, 0.f, 0.f};
            acc[i][j] = z;
        }

    const unsigned short* abase =
        Xb + (size_t)(bm * 128 + wid * 16 + (lane >> 2)) * KDIM + (lane & 3) * 8;
    const unsigned short* bbase =
        Wt + (size_t)(bn * 128 + wid * 16 + (lane >> 2)) * KDIM + (lane & 3) * 8;

    for (int kt = 0; kt < KDIM; kt += 32) {
#pragma unroll
        for (int j = 0; j < 2; ++j)
            __builtin_amdgcn_global_load_lds(
                (const __attribute__((address_space(1))) unsigned int*)(abase + (size_t)j * 64 * KDIM + kt),
                (__attribute__((address_space(3))) unsigned int*)(&As[j * 64 + wid * 16][0]),
                16, 0, 0);
#pragma unroll
        for (int j = 0; j < 2; ++j)
            __builtin_amdgcn_global_load_lds(
                (const __attribute__((address_space(1))) unsigned int*)(bbase + (size_t)j * 64 * KDIM + kt),
                (__attribute__((address_space(3))) unsigned int*)(&Bs[j * 64 + wid * 16][0]),
                16, 0, 0);
        __syncthreads();

        short8 af[4], bfr[4];
#pragma unroll
        for (int mi = 0; mi < 4; ++mi)
            af[mi] = *(const short8*)&As[wr * 64 + mi * 16 + (lane & 15)][(lane >> 4) * 8];
#pragma unroll
        for (int ni = 0; ni < 4; ++ni)
            bfr[ni] = *(const short8*)&Bs[wc * 64 + ni * 16 + (lane & 15)][(lane >> 4) * 8];

#pragma unroll
        for (int mi = 0; mi < 4; ++mi)
#pragma unroll
            for (int ni = 0; ni < 4; ++ni)
                acc[mi][ni] = MFMA16(af[mi], bfr[ni], acc[mi][ni]);

        __syncthreads();
    }

#pragma unroll
    for (int ni = 0; ni < 4; ++ni) {
        const int col = bn * 128 + wc * 64 + ni * 16 + (lane & 15);
        if (col < NDIM) {
            const float bv = bias[col];
#pragma unroll
            for (int mi = 0; mi < 4; ++mi) {
                const int row = bm * 128 + wr * 64 + mi * 16 + ((lane >> 4) << 2);
                float* op = out + (size_t)row * NDIM + col;
#pragma unroll
                for (int r = 0; r < 4; ++r)
                    op[(size_t)r * NDIM] = acc[mi][ni][r] + bv;
            }
        }
    }
}

// ---------------------------------------------------------------------------
// Kernel 3: activation. One wave per (row, span of 51 cols).
// ---------------------------------------------------------------------------
__global__ void act_kernel(const float* __restrict__ outp,
                           const float* __restrict__ u,
                           float* __restrict__ dt) {
    const int lane  = threadIdx.x & 63;
    const int gwave = (blockIdx.x * 256 + threadIdx.x) >> 6;
    const int nwave = gridDim.x * 4;
    const int total = MDIM * 20;
    const float NEG_INF = -__builtin_inff();

    for (int unit = gwave; unit < total; unit += nwave) {
        const int row = unit / 20;
        const int sp  = unit - row * 20;
        const size_t base = (size_t)row * NDIM + sp * 51;

        float o = 0.f, uu = 0.5f;
        if (lane < 51) {
            o  = outp[base + lane];
            uu = u[base + lane];
        }
        const bool soft = (lane >= 1) && (lane < 51);

        const float uc = fmaxf(uu, 1e-9f);
        const float g  = -__logf(-__logf(uc));
        float z = soft ? (o + g) * 5.0f : NEG_INF;

        float m = z;
#pragma unroll
        for (int off = 32; off; off >>= 1) m = fmaxf(m, __shfl_xor(m, off));
        float e = soft ? __expf(z - m) : 0.f;
        float s = e;
#pragma unroll
        for (int off = 32; off; off >>= 1) s += __shfl_xor(s, off);

        float res;
        if (lane == 0) {
            const float ex = __expf(-2.0f * fabsf(o));
            const float t  = (1.0f - ex) / (1.0f + ex);
            res = copysignf(t, o);
        } else {
            res = e / s;
        }
        if (lane < 51) dt[base + lane] = res;
    }
}

// ---------------------------------------------------------------------------
extern "C" void kernel_launch(void* const* d_in, const int* in_sizes, int n_in,
                              void* d_out, int out_size, void* d_ws, size_t ws_size,
                              hipStream_t stream) {
    const float* x = (const float*)d_in[0];
    const float* W = (const float*)d_in[1];
    const float* b = (const float*)d_in[2];
    const float* u = (const float*)d_in[3];
    float* out = (float*)d_out;                      // outputs [M][N]
    float* dt  = out + (size_t)MDIM * NDIM;          // data_t  [M][N]
    unsigned short* Wt = (unsigned short*)d_ws;      // bf16 [NPAD][K], 4 MiB
    unsigned short* Xb = Wt + (size_t)NPAD * KDIM;   // bf16 [M][K], 64 MiB

    prep_w_kernel<<<512, 256, 0, stream>>>(W, Wt);
    prep_x_kernel<<<2048, 256, 0, stream>>>(x, Xb);

    const hipError_t attr_ok = hipFuncSetAttribute(
        (const void*)gemm8_kernel, hipFuncAttributeMaxDynamicSharedMemorySize, 131072);
    if (attr_ok == hipSuccess) {
        gemm8_kernel<<<256, 512, 131072, stream>>>(Xb, Wt, b, out);
    } else {
        gemm_bf_kernel<<<dim3(8, 128), 256, 0, stream>>>(Xb, Wt, b, out);
    }

    act_kernel<<<8192, 256, 0, stream>>>(out, u, dt);
}

// Round 4
// 191.811 us; speedup vs baseline: 1.3078x; 1.0031x over previous
//
#include <hip/hip_runtime.h>
#include <stdint.h>

#define MDIM 16384
#define NDIM 1020
#define KDIM 2048
#define NPAD 1024
#define TK   (KDIM / 64)   // 32 K-tiles of BK=64

typedef __attribute__((ext_vector_type(4))) float f32x4;
typedef __attribute__((ext_vector_type(8))) short short8;

#define MFMA16(a, b, c) __builtin_amdgcn_mfma_f32_16x16x32_bf16((a), (b), (c), 0, 0, 0)

// asm ds_read_b128: register-only constraints -> SIInsertWaitcnts does NOT
// insert conservative vmcnt waits (pointer ds_reads aliasing outstanding
// LDS-DMA writes get silently drained; that was R3's 3x stall). Waits are
// issued manually: s_barrier; s_waitcnt lgkmcnt(0); sched_barrier(0).
template <int OFF>
static __device__ __forceinline__ short8 dsr(unsigned addr) {
    short8 r;
    asm volatile("ds_read_b128 %0, %1 offset:%2" : "=v"(r) : "v"(addr), "i"(OFF));
    return r;
}

// f32 -> bf16 round-to-nearest-even
__device__ __forceinline__ unsigned short f2bf(float f) {
    unsigned int u = __float_as_uint(f);
    unsigned int r = (u + 0x7FFFu + ((u >> 16) & 1u)) >> 16;
    return (unsigned short)r;
}

// ---------------------------------------------------------------------------
// Kernel 1: W [K=2048][N=1020] f32 -> Wt [NPAD=1024][K=2048] bf16 (transposed)
// ---------------------------------------------------------------------------
__global__ void prep_w_kernel(const float* __restrict__ W,
                              unsigned short* __restrict__ Wt) {
    const int id = blockIdx.x * 256 + threadIdx.x;  // 512 blocks * 256
    const int n0 = (id & 255) * 4;
    const int k0 = (id >> 8) * 4;
    float a[4][4];
    if (n0 < NDIM) {
#pragma unroll
        for (int i = 0; i < 4; ++i) {
            const float* p = W + (size_t)(k0 + i) * NDIM + n0;
            a[i][0] = p[0]; a[i][1] = p[1]; a[i][2] = p[2]; a[i][3] = p[3];
        }
    } else {
#pragma unroll
        for (int i = 0; i < 4; ++i)
#pragma unroll
            for (int j = 0; j < 4; ++j) a[i][j] = 0.f;
    }
#pragma unroll
    for (int j = 0; j < 4; ++j) {
        uint2 p;
        p.x = (unsigned)f2bf(a[0][j]) | ((unsigned)f2bf(a[1][j]) << 16);
        p.y = (unsigned)f2bf(a[2][j]) | ((unsigned)f2bf(a[3][j]) << 16);
        *(uint2*)(Wt + (size_t)(n0 + j) * KDIM + k0) = p;
    }
}

// ---------------------------------------------------------------------------
// Kernel 1b: x [M][K] f32 -> Xb [M][K] bf16
// ---------------------------------------------------------------------------
__global__ void prep_x_kernel(const float* __restrict__ x,
                              unsigned short* __restrict__ Xb) {
    const size_t total = (size_t)MDIM * KDIM;
    const size_t stride = (size_t)gridDim.x * 256 * 8;
    for (size_t i = ((size_t)blockIdx.x * 256 + threadIdx.x) * 8; i < total; i += stride) {
        const float4 v0 = *(const float4*)(x + i);
        const float4 v1 = *(const float4*)(x + i + 4);
        uint4 p;
        p.x = (unsigned)f2bf(v0.x) | ((unsigned)f2bf(v0.y) << 16);
        p.y = (unsigned)f2bf(v0.z) | ((unsigned)f2bf(v0.w) << 16);
        p.z = (unsigned)f2bf(v1.x) | ((unsigned)f2bf(v1.y) << 16);
        p.w = (unsigned)f2bf(v1.z) | ((unsigned)f2bf(v1.w) << 16);
        *(uint4*)(Xb + i) = p;
    }
}

// ---------------------------------------------------------------------------
// Kernel 2: 256x256 8-phase GEMM, BK=64, 512 thr / 8 waves (2 wr x 4 wc),
// per-wave C = 128x64 = 8mf x 4nf frags of 16x16. Same schedule as R3; the
// only change is asm ds_reads + explicit lgkmcnt(0) per phase (see dsr()).
// Stage schedule per K-tile t (stripe = 64 rows = 1 gload/wave):
//   p0: A-stripes 1,3 (t+1)->nb | p1: B 0,1 (t+2)->buf
//   p2: B 2,3 (t+2)->buf        | p3: A 0,2 (t+2)->buf, vmcnt(4)
// vmcnt(4) at p3 retires everything through (t,p1) => Kt t+1 fully landed.
// LDS swizzle: 16B block cb stored at (row, cb^(row&7)); reads conflict-free.
// ---------------------------------------------------------------------------
extern "C" __global__ __launch_bounds__(512, 2) void gemm8_kernel(
    const unsigned short* __restrict__ Xb,
    const unsigned short* __restrict__ Wt,
    const float* __restrict__ bias,
    float* __restrict__ out) {
    extern __shared__ unsigned short lds_raw[];  // 2 bufs x (A 256x64 + B 256x64)

    const int tid  = threadIdx.x;
    const int lane = tid & 63;
    const int wid  = tid >> 6;   // 0..7
    const int wr   = wid >> 2;   // 0..1 (M)
    const int wc   = wid & 3;    // 0..3 (N)

    // XCD-aware swizzle: 256 blocks, 8 XCDs, 32 consecutive per XCD
    const int bid = blockIdx.x;
    const int swz = (bid & 7) * 32 + (bid >> 3);
    const int bm  = swz >> 2;    // 0..63
    const int bn  = swz & 3;     // 0..3

    // per-lane pre-swizzled staging source (rule 21): row = wid*8 + (lane>>3),
    // k-block = (lane&7)^(lane>>3) (inverse of the read-side XOR swizzle)
    const int srow = wid * 8 + (lane >> 3);
    const int scb  = ((lane & 7) ^ (lane >> 3)) * 8;
    const unsigned short* aS = Xb + (size_t)(bm * 256 + srow) * KDIM + scb;
    const unsigned short* bS = Wt + (size_t)(bn * 256 + srow) * KDIM + scb;

#define STAGE(BUFI, OP, STRIPE, S) do {                                          \
    const size_t ks_ = (size_t)(((S) * 64) & (KDIM - 1));                        \
    const unsigned short* sp_ =                                                  \
        ((OP) ? bS : aS) + (size_t)((STRIPE) * 64) * KDIM + ks_;                 \
    __builtin_amdgcn_global_load_lds(                                            \
        (const __attribute__((address_space(1))) unsigned int*)sp_,              \
        (__attribute__((address_space(3))) unsigned int*)(lds_raw +              \
            (BUFI) * 32768 + (OP) * 16384 + ((STRIPE) * 64 + wid * 8) * 64),     \
        16, 0, 0);                                                               \
} while (0)

#define VMCNT4 do {                                                              \
    asm volatile("s_waitcnt vmcnt(4)" ::: "memory");                             \
    __builtin_amdgcn_sched_barrier(0);                                           \
} while (0)

    // LDS read addressing (byte offsets; swizzled k-block cb = kb ^ (row&7)):
    //   A frag(mf,k2): byte = buf*65536 + (wr*128 + mf*16 + l15)*128
    //                         + (((k2*4+hi) ^ l7) << 4)
    //   B frag(nf,k2): byte = buf*65536 + 32768 + (wc*64 + nf*16 + l15)*128
    //                         + (((k2*4+hi) ^ l7) << 4)
    const unsigned ldsbase =
        (unsigned)(uintptr_t)(__attribute__((address_space(3))) unsigned short*)lds_raw;
    const unsigned l15 = lane & 15, hi = lane >> 4, l7 = lane & 7;
    const unsigned c0 = (unsigned)((0 * 4 + hi) ^ l7) << 4;
    const unsigned c1 = (unsigned)((1 * 4 + hi) ^ l7) << 4;
    const unsigned pbA = ldsbase + (unsigned)(wr * 128 + l15) * 128;
    const unsigned pbB = ldsbase + 32768u + (unsigned)(wc * 64 + l15) * 128;

    f32x4 acc[8][4];
#pragma unroll
    for (int i = 0; i < 8; ++i)
#pragma unroll
        for (int j = 0; j < 4; ++j) {
            f32x4 z = {0.f, 0.f, 0.f, 0.f};
            acc[i][j] = z;
        }

    // ---- prologue: Kt0 all 8 stripes; Kt1 B0-3, A0, A2 (FIFO order) ----
    STAGE(0, 0, 0, 0); STAGE(0, 0, 1, 0); STAGE(0, 0, 2, 0); STAGE(0, 0, 3, 0);
    STAGE(0, 1, 0, 0); STAGE(0, 1, 1, 0); STAGE(0, 1, 2, 0); STAGE(0, 1, 3, 0);
    STAGE(1, 1, 0, 1); STAGE(1, 1, 1, 1); STAGE(1, 1, 2, 1); STAGE(1, 1, 3, 1);
    STAGE(1, 0, 0, 1); STAGE(1, 0, 2, 1);
    VMCNT4;                                  // Kt0 fully landed
    __builtin_amdgcn_s_barrier();

#define PH_TAIL                                                       \
    __builtin_amdgcn_s_barrier();                                     \
    asm volatile("s_waitcnt lgkmcnt(0)" ::: "memory");                \
    __builtin_amdgcn_sched_barrier(0);                                \
    __builtin_amdgcn_s_setprio(1);

#define PH_MFMA(MF0)                                                  \
    _Pragma("unroll")                                                 \
    for (int nf = 0; nf < 4; ++nf) {                                  \
        acc[MF0][nf]     = MFMA16(af0[0], bfv[nf][0], acc[MF0][nf]);      \
        acc[MF0][nf]     = MFMA16(af0[1], bfv[nf][1], acc[MF0][nf]);      \
        acc[MF0 + 1][nf] = MFMA16(af1[0], bfv[nf][0], acc[MF0 + 1][nf]);  \
        acc[MF0 + 1][nf] = MFMA16(af1[1], bfv[nf][1], acc[MF0 + 1][nf]);  \
    }                                                                 \
    __builtin_amdgcn_sched_barrier(0);                                \
    __builtin_amdgcn_s_setprio(0);

#define RDA(MF0)                                                      \
    af0[0] = dsr<(MF0) * 2048>(aadr0);                                \
    af0[1] = dsr<(MF0) * 2048>(aadr1);                                \
    af1[0] = dsr<(MF0) * 2048 + 2048>(aadr0);                         \
    af1[1] = dsr<(MF0) * 2048 + 2048>(aadr1);

#define RDB(NF)                                                       \
    bfv[NF][0] = dsr<(NF) * 2048>(badr0);                             \
    bfv[NF][1] = dsr<(NF) * 2048>(badr1);

    for (int t = 0; t < TK; ++t) {
        const int buf = t & 1;
        const int nb  = buf ^ 1;
        const unsigned bo = (unsigned)buf << 16;
        const unsigned aadr0 = pbA + bo + c0, aadr1 = pbA + bo + c1;
        const unsigned badr0 = pbB + bo + c0, badr1 = pbB + bo + c1;
        short8 bfv[4][2];
        short8 af0[2], af1[2];

        // ---- phase 0: all B frags + A mf{0,1}; stage A-stripes 1,3 (t+1) ----
        RDB(0) RDB(1) RDB(2) RDB(3)
        RDA(0)
        STAGE(nb, 0, 1, t + 1);
        STAGE(nb, 0, 3, t + 1);
        PH_TAIL
        PH_MFMA(0)
        __builtin_amdgcn_s_barrier();

        // ---- phase 1: A mf{2,3}; stage B-stripes 0,1 (t+2) ----
        RDA(2)
        STAGE(buf, 1, 0, t + 2);
        STAGE(buf, 1, 1, t + 2);
        PH_TAIL
        PH_MFMA(2)
        __builtin_amdgcn_s_barrier();

        // ---- phase 2: A mf{4,5}; stage B-stripes 2,3 (t+2) ----
        RDA(4)
        STAGE(buf, 1, 2, t + 2);
        STAGE(buf, 1, 3, t + 2);
        PH_TAIL
        PH_MFMA(4)
        __builtin_amdgcn_s_barrier();

        // ---- phase 3: A mf{6,7}; stage A-stripes 0,2 (t+2); vmcnt(4) ----
        RDA(6)
        STAGE(buf, 0, 0, t + 2);
        STAGE(buf, 0, 2, t + 2);
        PH_TAIL
        PH_MFMA(6)
        VMCNT4;
        __builtin_amdgcn_s_barrier();
    }

    // ---- epilogue: bias + store (C/D: col=lane&15, row=(lane>>4)*4+r) ----
#pragma unroll
    for (int nf = 0; nf < 4; ++nf) {
        const int col = bn * 256 + wc * 64 + nf * 16 + (lane & 15);
        if (col < NDIM) {
            const float bv = bias[col];
#pragma unroll
            for (int mf = 0; mf < 8; ++mf) {
                const int row = bm * 256 + wr * 128 + mf * 16 + ((lane >> 4) << 2);
                float* op = out + (size_t)row * NDIM + col;
#pragma unroll
                for (int r = 0; r < 4; ++r)
                    op[(size_t)r * NDIM] = acc[mf][nf][r] + bv;
            }
        }
    }
#undef STAGE
#undef VMCNT4
#undef PH_TAIL
#undef PH_MFMA
#undef RDA
#undef RDB
}

// ---------------------------------------------------------------------------
// Fallback GEMM (static 64 KiB LDS) if dynamic-LDS attr fails
// ---------------------------------------------------------------------------
__global__ void gemm_bf_kernel(const unsigned short* __restrict__ Xb,
                               const unsigned short* __restrict__ Wt,
                               const float* __restrict__ bias,
                               float* __restrict__ out) {
    __shared__ __align__(16) unsigned short As[128][32];
    __shared__ __align__(16) unsigned short Bs[128][32];

    const int tid  = threadIdx.x;
    const int lane = tid & 63;
    const int wid  = tid >> 6;
    const int wr   = wid >> 1;
    const int wc   = wid & 1;
    const int bn   = blockIdx.x;
    const int bm   = blockIdx.y;

    f32x4 acc[4][4];
#pragma unroll
    for (int i = 0; i < 4; ++i)
#pragma unroll
        for (int j = 0; j < 4; ++j) {
            f32x4 z = {0.f, 0.f, 0.f, 0.f};
            acc[i][j] = z;
        }

    const unsigned short* abase =
        Xb + (size_t)(bm * 128 + wid * 16 + (lane >> 2)) * KDIM + (lane & 3) * 8;
    const unsigned short* bbase =
        Wt + (size_t)(bn * 128 + wid * 16 + (lane >> 2)) * KDIM + (lane & 3) * 8;

    for (int kt = 0; kt < KDIM; kt += 32) {
#pragma unroll
        for (int j = 0; j < 2; ++j)
            __builtin_amdgcn_global_load_lds(
                (const __attribute__((address_space(1))) unsigned int*)(abase + (size_t)j * 64 * KDIM + kt),
                (__attribute__((address_space(3))) unsigned int*)(&As[j * 64 + wid * 16][0]),
                16, 0, 0);
#pragma unroll
        for (int j = 0; j < 2; ++j)
            __builtin_amdgcn_global_load_lds(
                (const __attribute__((address_space(1))) unsigned int*)(bbase + (size_t)j * 64 * KDIM + kt),
                (__attribute__((address_space(3))) unsigned int*)(&Bs[j * 64 + wid * 16][0]),
                16, 0, 0);
        __syncthreads();

        short8 af[4], bfr[4];
#pragma unroll
        for (int mi = 0; mi < 4; ++mi)
            af[mi] = *(const short8*)&As[wr * 64 + mi * 16 + (lane & 15)][(lane >> 4) * 8];
#pragma unroll
        for (int ni = 0; ni < 4; ++ni)
            bfr[ni] = *(const short8*)&Bs[wc * 64 + ni * 16 + (lane & 15)][(lane >> 4) * 8];

#pragma unroll
        for (int mi = 0; mi < 4; ++mi)
#pragma unroll
            for (int ni = 0; ni < 4; ++ni)
                acc[mi][ni] = MFMA16(af[mi], bfr[ni], acc[mi][ni]);

        __syncthreads();
    }

#pragma unroll
    for (int ni = 0; ni < 4; ++ni) {
        const int col = bn * 128 + wc * 64 + ni * 16 + (lane & 15);
        if (col < NDIM) {
            const float bv = bias[col];
#pragma unroll
            for (int mi = 0; mi < 4; ++mi) {
                const int row = bm * 128 + wr * 64 + mi * 16 + ((lane >> 4) << 2);
                float* op = out + (size_t)row * NDIM + col;
#pragma unroll
                for (int r = 0; r < 4; ++r)
                    op[(size_t)r * NDIM] = acc[mi][ni][r] + bv;
            }
        }
    }
}

// ---------------------------------------------------------------------------
// Kernel 3: activation. One wave per (row, span of 51 cols).
// ---------------------------------------------------------------------------
__global__ void act_kernel(const float* __restrict__ outp,
                           const float* __restrict__ u,
                           float* __restrict__ dt) {
    const int lane  = threadIdx.x & 63;
    const int gwave = (blockIdx.x * 256 + threadIdx.x) >> 6;
    const int nwave = gridDim.x * 4;
    const int total = MDIM * 20;
    const float NEG_INF = -__builtin_inff();

    for (int unit = gwave; unit < total; unit += nwave) {
        const int row = unit / 20;
        const int sp  = unit - row * 20;
        const size_t base = (size_t)row * NDIM + sp * 51;

        float o = 0.f, uu = 0.5f;
        if (lane < 51) {
            o  = outp[base + lane];
            uu = u[base + lane];
        }
        const bool soft = (lane >= 1) && (lane < 51);

        const float uc = fmaxf(uu, 1e-9f);
        const float g  = -__logf(-__logf(uc));
        float z = soft ? (o + g) * 5.0f : NEG_INF;

        float m = z;
#pragma unroll
        for (int off = 32; off; off >>= 1) m = fmaxf(m, __shfl_xor(m, off));
        float e = soft ? __expf(z - m) : 0.f;
        float s = e;
#pragma unroll
        for (int off = 32; off; off >>= 1) s += __shfl_xor(s, off);

        float res;
        if (lane == 0) {
            const float ex = __expf(-2.0f * fabsf(o));
            const float t  = (1.0f - ex) / (1.0f + ex);
            res = copysignf(t, o);
        } else {
            res = e / s;
        }
        if (lane < 51) dt[base + lane] = res;
    }
}

// ---------------------------------------------------------------------------
extern "C" void kernel_launch(void* const* d_in, const int* in_sizes, int n_in,
                              void* d_out, int out_size, void* d_ws, size_t ws_size,
                              hipStream_t stream) {
    const float* x = (const float*)d_in[0];
    const float* W = (const float*)d_in[1];
    const float* b = (const float*)d_in[2];
    const float* u = (const float*)d_in[3];
    float* out = (float*)d_out;                      // outputs [M][N]
    float* dt  = out + (size_t)MDIM * NDIM;          // data_t  [M][N]
    unsigned short* Wt = (unsigned short*)d_ws;      // bf16 [NPAD][K], 4 MiB
    unsigned short* Xb = Wt + (size_t)NPAD * KDIM;   // bf16 [M][K], 64 MiB

    prep_w_kernel<<<512, 256, 0, stream>>>(W, Wt);
    prep_x_kernel<<<2048, 256, 0, stream>>>(x, Xb);

    const hipError_t attr_ok = hipFuncSetAttribute(
        (const void*)gemm8_kernel, hipFuncAttributeMaxDynamicSharedMemorySize, 131072);
    if (attr_ok == hipSuccess) {
        gemm8_kernel<<<256, 512, 131072, stream>>>(Xb, Wt, b, out);
    } else {
        gemm_bf_kernel<<<dim3(8, 128), 256, 0, stream>>>(Xb, Wt, b, out);
    }

    act_kernel<<<8192, 256, 0, stream>>>(out, u, dt);
}